// Round 11
// baseline (158.492 us; speedup 1.0000x reference)
//
#include <hip/hip_runtime.h>
#include <hip/hip_bf16.h>

typedef __attribute__((ext_vector_type(8))) short bf16x8;
typedef __attribute__((ext_vector_type(4))) float f32x4;
typedef unsigned short u16;

#define B_  2
#define T_  2048
#define C_  1024
#define H_  16
#define HD_ 64

static __device__ __forceinline__ u16 f2bf(float f) {
  unsigned u = __float_as_uint(f);
  u += 0x7fffu + ((u >> 16) & 1u);   // round-to-nearest-even
  return (u16)(u >> 16);
}

// ---------------------------------------------------------------------------
// Kernel 0 "prep": two regions in one dispatch (round-8 version)
// ---------------------------------------------------------------------------
#define NW4 524288    // W float4 count
__global__ __launch_bounds__(256) void prep(
    const float* __restrict__ X, const float* __restrict__ W,
    u16* __restrict__ Xb, u16* __restrict__ Wb,
    u16* __restrict__ Vf, float* __restrict__ SubP64)
{
  __shared__ u16 tr[64][65];
  __shared__ float cs[4][64];
  const int blk = blockIdx.x;
  const int tid = threadIdx.x;

  if (blk < 1024) {                       // ---- pack + convert-X + colsums ----
    const int kt = blk & 31, bh = blk >> 5;
    const int b = bh >> 4, h = bh & 15;
    const int w = tid >> 6, lane = tid & 63;
    {
      const int row = tid >> 2;            // 0..63
      const int c0  = (tid & 3) * 16;      // float col base
      const float* xp = X + ((size_t)b * T_ + kt * 64 + row) * C_ + h * 64 + c0;
      float vals[16];
#pragma unroll
      for (int q = 0; q < 4; ++q) {
        float4 v = *(const float4*)(xp + q * 4);
        vals[q * 4 + 0] = v.x; vals[q * 4 + 1] = v.y;
        vals[q * 4 + 2] = v.z; vals[q * 4 + 3] = v.w;
      }
      u16 xb[16];
#pragma unroll
      for (int i = 0; i < 16; ++i) xb[i] = f2bf(vals[i]);
      u16* xq = Xb + ((size_t)(b * T_ + kt * 64 + row)) * C_ + h * 64 + c0;
      *(bf16x8*)xq       = *(const bf16x8*)&xb[0];
      *(bf16x8*)(xq + 8) = *(const bf16x8*)&xb[8];
#pragma unroll
      for (int i = 0; i < 16; ++i) tr[row][c0 + i] = xb[i];
#pragma unroll
      for (int m = 4; m <= 32; m <<= 1)
#pragma unroll
        for (int i = 0; i < 16; ++i) vals[i] += __shfl_xor(vals[i], m);
      if (lane < 4) {
        float* dst = &cs[w][lane * 16];
#pragma unroll
        for (int q = 0; q < 4; ++q) {
          f32x4 s4 = { vals[q * 4 + 0], vals[q * 4 + 1], vals[q * 4 + 2], vals[q * 4 + 3] };
          *(f32x4*)&dst[q * 4] = s4;
        }
      }
    }
    __syncthreads();
    {
      const int quad = (lane >> 4), l16 = lane & 15;
      u16* outb = Vf + ((size_t)bh * 32 + kt) * 4096;
#pragma unroll
      for (int c = 0; c < 2; ++c) {
        u16 tmp[8];
#pragma unroll
        for (int j = 0; j < 8; ++j) tmp[j] = tr[c * 32 + quad * 8 + j][w * 16 + l16];
        *(bf16x8*)&outb[((w * 2 + c) * 64 + lane) * 8] = *(const bf16x8*)tmp;
      }
    }
    if (tid < 64)
      SubP64[(size_t)bh * 2048 + kt * 64 + tid] =
          cs[0][tid] + cs[1][tid] + cs[2][tid] + cs[3][tid];
  } else {                                // ---- convert W ----
    int i = (blk - 1024) * 256 + tid;
    float4 v = ((const float4*)W)[i];
    ushort4 u = { f2bf(v.x), f2bf(v.y), f2bf(v.z), f2bf(v.w) };
    ((ushort4*)Wb)[i] = u;
  }
}

// ---------------------------------------------------------------------------
// Kernel 1: gemm (round-10 LDS double-buffered version, unchanged).
// ---------------------------------------------------------------------------
__global__ __launch_bounds__(256) void gemm_qk(
    const u16* __restrict__ Xb, const u16* __restrict__ Wb,
    u16* __restrict__ Qo, u16* __restrict__ Kf)
{
  __shared__ __align__(16) u16 As[2][128 * 64];
  __shared__ __align__(16) u16 Bs[2][128 * 64];

  const int tid  = threadIdx.x;
  const int w    = tid >> 6;
  const int lane = tid & 63;
  const int quad = lane >> 4;
  const int l16  = lane & 15;
  const int m0 = blockIdx.y * 128;
  const int n0 = blockIdx.x * 128;

  const int grow = w * 8 + ((lane >> 3) & 7);
  const int gcol = (lane & 7) * 8;

  f32x4 zero = {0.f, 0.f, 0.f, 0.f};
  f32x4 acc[4][4];
#pragma unroll
  for (int i = 0; i < 4; ++i)
#pragma unroll
    for (int j = 0; j < 4; ++j) acc[i][j] = zero;

  const int wr = (w >> 1) * 64, wc = (w & 1) * 64;

  const u16* gax = Xb + (size_t)(m0 + grow) * C_ + gcol;
  const u16* gbx = Wb + (size_t)(n0 + grow) * C_ + gcol;

#define GISSUE(K, BUF)                                                      \
  {                                                                         \
    _Pragma("unroll") for (int r = 0; r < 4; ++r) {                         \
      __builtin_amdgcn_global_load_lds(                                     \
          (const __attribute__((address_space(1))) void*)(gax + (size_t)r * 32 * C_ + (K)), \
          (__attribute__((address_space(3))) void*)&As[BUF][(w * 8 + r * 32) * 64], \
          16, 0, 0);                                                        \
      __builtin_amdgcn_global_load_lds(                                     \
          (const __attribute__((address_space(1))) void*)(gbx + (size_t)r * 32 * C_ + (K)), \
          (__attribute__((address_space(3))) void*)&Bs[BUF][(w * 8 + r * 32) * 64], \
          16, 0, 0);                                                        \
    }                                                                       \
  }

  GISSUE(0, 0);
#pragma unroll 2
  for (int it = 0; it < 16; ++it) {
    const int cur = it & 1;
    __syncthreads();
    if (it < 15) GISSUE((it + 1) * 64, cur ^ 1);
#pragma unroll
    for (int c = 0; c < 2; ++c) {
      bf16x8 af[4], bf[4];
#pragma unroll
      for (int i = 0; i < 4; ++i)
        af[i] = *(const bf16x8*)&As[cur][(wr + i * 16 + l16) * 64 + c * 32 + quad * 8];
#pragma unroll
      for (int j = 0; j < 4; ++j)
        bf[j] = *(const bf16x8*)&Bs[cur][(wc + j * 16 + l16) * 64 + c * 32 + quad * 8];
#pragma unroll
      for (int i = 0; i < 4; ++i)
#pragma unroll
        for (int j = 0; j < 4; ++j)
          acc[i][j] = __builtin_amdgcn_mfma_f32_16x16x32_bf16(af[i], bf[j], acc[i][j], 0, 0, 0);
    }
  }
#undef GISSUE

#pragma unroll
  for (int i = 0; i < 4; ++i) {
    const int t_base = m0 + wr + i * 16;
    const int bidx = t_base >> 11;
    const int kt   = (t_base & 2047) >> 6;
    const int trow = (t_base & 2047) + quad * 4;
#pragma unroll
    for (int j = 0; j < 4; ++j) {
      const int n = n0 + wc + j * 16 + l16;
      if (n < C_) {
        const int hq = n >> 6, d = n & 63;
        u16* qp = Qo + (((size_t)bidx * H_ + hq) * T_ + trow) * HD_ + d;
#pragma unroll
        for (int r = 0; r < 4; ++r) qp[(size_t)r * HD_] = f2bf(0.125f * acc[i][j][r]);
      } else {
        const int nh = n - C_;
        const int hh = nh >> 6, d = nh & 63;
        u16* kp = Kf + (((((size_t)(bidx * H_ + hh) * 32 + kt) * 4 + i) * 2 + (d >> 5)) * 64
                        + ((d >> 3) & 3) * 16 + quad * 4) * 8 + (d & 7);
#pragma unroll
        for (int r = 0; r < 4; ++r) kp[(size_t)r * 8] = f2bf(acc[i][j][r]);
      }
    }
  }
}

// ---------------------------------------------------------------------------
// Kernel 2: paired flash attention. Block = 512 threads = two independent
// 4-wave teams: team 0 -> qt = 31-p, team 1 -> qt = p  (uniform 33 tiles
// per block, 2 blocks/CU, 16 waves/CU sustained - no triangle decay).
// Teams share only the epilogue barrier sequence.
// ---------------------------------------------------------------------------
__device__ __forceinline__ void load_kv(
    bf16x8 (&kf)[2][4], bf16x8 (&vf)[2][4],
    const u16* __restrict__ kbase, const u16* __restrict__ vbase, int lane)
{
#pragma unroll
  for (int c = 0; c < 2; ++c)
#pragma unroll
    for (int nb = 0; nb < 4; ++nb) {
      kf[c][nb] = *(const bf16x8*)&kbase[((nb * 2 + c) * 64 + lane) * 8];
      vf[c][nb] = *(const bf16x8*)&vbase[((nb * 2 + c) * 64 + lane) * 8];
    }
}

__device__ __forceinline__ void tile_compute(
    const bf16x8 (&qfrag)[2], const bf16x8 (&kf)[2][4], const bf16x8 (&vf)[2][4],
    f32x4 (&acc)[4], f32x4& accl, float (*pb)[68],
    int quad, int l16, int myrow, bool diag, bf16x8 onesf)
{
  f32x4 zero = {0.f, 0.f, 0.f, 0.f};
  f32x4 sfr[4] = {zero, zero, zero, zero};
#pragma unroll
  for (int cc = 0; cc < 2; ++cc)
#pragma unroll
    for (int nb = 0; nb < 4; ++nb)
      sfr[nb] = __builtin_amdgcn_mfma_f32_16x16x32_bf16(qfrag[cc], kf[cc][nb], sfr[nb], 0, 0, 0);

#pragma unroll
  for (int nb = 0; nb < 4; ++nb)
#pragma unroll
    for (int r = 0; r < 4; ++r) {
      float p = __expf(sfr[nb][r]);
      if (diag && (nb * 16 + l16 > myrow + r)) p = 0.f;
      pb[quad * 4 + r][nb * 16 + l16] = p;
    }

#pragma unroll
  for (int cc = 0; cc < 2; ++cc) {
    f32x4 plo = *(const f32x4*)&pb[l16][cc * 32 + quad * 8];
    f32x4 phi = *(const f32x4*)&pb[l16][cc * 32 + quad * 8 + 4];
    union { unsigned u[4]; bf16x8 v; } pk;
    __hip_bfloat162 hh;
    hh = __float22bfloat162_rn(make_float2(plo[0], plo[1])); pk.u[0] = *(unsigned*)&hh;
    hh = __float22bfloat162_rn(make_float2(plo[2], plo[3])); pk.u[1] = *(unsigned*)&hh;
    hh = __float22bfloat162_rn(make_float2(phi[0], phi[1])); pk.u[2] = *(unsigned*)&hh;
    hh = __float22bfloat162_rn(make_float2(phi[2], phi[3])); pk.u[3] = *(unsigned*)&hh;
    accl = __builtin_amdgcn_mfma_f32_16x16x32_bf16(pk.v, onesf, accl, 0, 0, 0);
#pragma unroll
    for (int nb = 0; nb < 4; ++nb)
      acc[nb] = __builtin_amdgcn_mfma_f32_16x16x32_bf16(pk.v, vf[cc][nb], acc[nb], 0, 0, 0);
  }
}

__global__ __launch_bounds__(512) void attn_kernel(
    const u16* __restrict__ Q, const u16* __restrict__ Kf, const u16* __restrict__ Vf,
    const float* __restrict__ SubP64, const float* __restrict__ X, float* __restrict__ out,
    const float* __restrict__ alphap, const float* __restrict__ betap,
    const float* __restrict__ gammap)
{
  // per team: pbuf 4x16x68 f32 (17408) aliased w/ epilogue Xt, + G/GP (2048)
  __shared__ __align__(16) char smem[2 * 19456];

  const int tid  = threadIdx.x;
  const int team = tid >> 8;             // 0 or 1
  const int ttid = tid & 255;
  const int w    = ttid >> 6;
  const int lane = tid & 63;
  const int quad = lane >> 4;
  const int l16  = lane & 15;
  const int p  = blockIdx.y;             // 0..15
  const int qt = team ? p : 31 - p;
  const int bh = blockIdx.x;
  const int b = bh >> 4, h = bh & 15;
  char* tsm = smem + team * 19456;

  const u16* kfb = Kf + (size_t)bh * T_ * HD_;
  const u16* vfb = Vf + (size_t)bh * T_ * HD_;

  bf16x8 qfrag[2];
  {
    const u16* qp = Q + ((size_t)bh * T_ + qt * 64 + w * 16 + l16) * HD_ + quad * 8;
    qfrag[0] = *(const bf16x8*)qp;
    qfrag[1] = *(const bf16x8*)(qp + 32);
  }

  bf16x8 onesf;
#pragma unroll
  for (int j = 0; j < 8; ++j) onesf[j] = (short)0x3F80;

  f32x4 zero = {0.f, 0.f, 0.f, 0.f};
  f32x4 acc[4] = {zero, zero, zero, zero};
  f32x4 accl = zero;
  const int myrow = w * 16 + quad * 4;
  float (*pb)[68] = (float(*)[68])((float*)tsm + (size_t)w * 16 * 68);

  bf16x8 kA[2][4], vA[2][4], kB[2][4], vB[2][4];
  load_kv(kA, vA, kfb, vfb, lane);
  int kt = 0;
  for (;;) {
    int ktn = (kt + 1 < qt) ? kt + 1 : qt;
    load_kv(kB, vB, kfb + (size_t)ktn * 4096, vfb + (size_t)ktn * 4096, lane);
    tile_compute(qfrag, kA, vA, acc, accl, pb, quad, l16, myrow, kt == qt, onesf);
    if (kt + 1 > qt) break;
    int ktn2 = (kt + 2 < qt) ? kt + 2 : qt;
    load_kv(kA, vA, kfb + (size_t)ktn2 * 4096, vfb + (size_t)ktn2 * 4096, lane);
    tile_compute(qfrag, kB, vB, acc, accl, pb, quad, l16, myrow, kt + 1 == qt, onesf);
    kt += 2;
    if (kt > qt) break;
  }

  // ---------------- fused epilogue (per team; block-wide barriers) --------
  __syncthreads();                        // both teams done with pbuf
  float* Xt = (float*)tsm;                // [64][68]
  float* G  = (float*)(tsm + 17408);      // [4][64]
  float* GP = (float*)(tsm + 18432);      // [4][64]

  {
    const int row = ttid >> 2, c0 = (ttid & 3) * 16;
    const float* xp = X + ((size_t)b * T_ + qt * 64 + row) * C_ + h * 64 + c0;
#pragma unroll
    for (int q = 0; q < 4; ++q) {
      float4 v = *(const float4*)(xp + q * 4);
      Xt[row * 68 + c0 + q * 4 + 0] = v.x;
      Xt[row * 68 + c0 + q * 4 + 1] = v.y;
      Xt[row * 68 + c0 + q * 4 + 2] = v.z;
      Xt[row * 68 + c0 + q * 4 + 3] = v.w;
    }
  }
  {
    float pp = 0.f;
    for (int i = w; i < qt; i += 4)
      pp += SubP64[(size_t)bh * 2048 + i * 64 + lane];
    GP[w * 64 + lane] = pp;
  }
  __syncthreads();
  {
    float g = 0.f;
#pragma unroll
    for (int i = 0; i < 16; ++i) g += Xt[(w * 16 + i) * 68 + lane];
    G[w * 64 + lane] = g;
  }
  __syncthreads();
  {
    const float alpha = *alphap, gamma = *gammap;
    float run = GP[lane] + GP[64 + lane] + GP[128 + lane] + GP[192 + lane];
    for (int g = 0; g < w; ++g) run += G[g * 64 + lane];
    const int tbase = qt * 64 + w * 16;
#pragma unroll
    for (int i = 0; i < 16; ++i) {
      float v = Xt[(w * 16 + i) * 68 + lane];
      run += v;
      Xt[(w * 16 + i) * 68 + lane] =
          alpha * v - gamma * run * __builtin_amdgcn_rcpf((float)(tbase + i + 1));
    }
  }
  __syncthreads();

  const float beta = *betap;
  float rl[4];
#pragma unroll
  for (int r = 0; r < 4; ++r) rl[r] = beta * __builtin_amdgcn_rcpf(accl[r]);
#pragma unroll
  for (int nb = 0; nb < 4; ++nb) {
#pragma unroll
    for (int r = 0; r < 4; ++r) {
      int t = qt * 64 + myrow + r;
      int d = nb * 16 + l16;
      out[((size_t)b * T_ + t) * C_ + h * 64 + d] =
          Xt[(myrow + r) * 68 + d] + rl[r] * acc[nb][r];
    }
  }
}

// ---------------------------------------------------------------------------
extern "C" void kernel_launch(void* const* d_in, const int* in_sizes, int n_in,
                              void* d_out, int out_size, void* d_ws, size_t ws_size,
                              hipStream_t stream) {
  const float* x      = (const float*)d_in[0];
  const float* W_attn = (const float*)d_in[1];
  const float* alphap = (const float*)d_in[2];
  const float* betap  = (const float*)d_in[3];
  const float* gammap = (const float*)d_in[4];
  float* out = (float*)d_out;

  // ws: Qb@0(8M) Kf@8(8M) Vf@16(8M) SubP64@24(.25M) Xb@25(8M) Wb@33(4M) = 37M
  char* ws = (char*)d_ws;
  u16*   Qb     = (u16*)(ws);
  u16*   Kfb    = (u16*)(ws + (8ull  << 20));
  u16*   Vfb    = (u16*)(ws + (16ull << 20));
  float* SubP64 = (float*)(ws + (24ull << 20));
  u16*   Xb     = (u16*)(ws + (25ull << 20));
  u16*   Wb     = (u16*)(ws + (33ull << 20));

  prep<<<3072, 256, 0, stream>>>(x, W_attn, Xb, Wb, Vfb, SubP64);
  gemm_qk<<<dim3(16, 32), 256, 0, stream>>>(Xb, Wb, Qb, Kfb);
  attn_kernel<<<dim3(32, 16), 512, 0, stream>>>(Qb, Kfb, Vfb, SubP64, x, out,
                                                alphap, betap, gammap);
}